// Round 5
// baseline (227.790 us; speedup 1.0000x reference)
//
#include <hip/hip_runtime.h>

constexpr int B = 16, N = 128, D = 128, DN0 = 64, DE0 = 16;

typedef _Float16 half8 __attribute__((ext_vector_type(8)));
typedef _Float16 half4 __attribute__((ext_vector_type(4)));
typedef float floatx4 __attribute__((ext_vector_type(4)));
typedef float floatx16 __attribute__((ext_vector_type(16)));

// async 16B global->LDS. msg0/T2 global layout is cell-swizzled
// (16B cell g of row j stored at g^(j&15)) so linear copies land
// conflict-free in LDS.
__device__ __forceinline__ void gld16(const _Float16* g, _Float16* l) {
  __builtin_amdgcn_global_load_lds(
      (const __attribute__((address_space(1))) void*)g,
      (__attribute__((address_space(3))) void*)l, 16, 0, 0);
}

// ---------------------------------------------------------------------------
// K1: merged prep. bid < 2048: xi0/xj0 row precompute (256 thr, output split).
// bid >= 2048 (128 blocks): WeT_l[c][k] = (fp16) w_msg_l[2D+k][c], l=1,2.
// NOTE (R15 lesson): tail GEMV weights stay in k-major layout — w[k*D+c] is
// coalesced ACROSS THE WAVE at each k.
// ---------------------------------------------------------------------------
__global__ __launch_bounds__(256) void k_pre(
    const float* __restrict__ x, const float* __restrict__ wm0,
    const float* __restrict__ bm0, const float* __restrict__ wm1,
    const float* __restrict__ wm2,
    float* __restrict__ xi0, float* __restrict__ xj0,
    _Float16* __restrict__ weT1, _Float16* __restrict__ weT2) {
  const int bid = blockIdx.x;
  const int t = threadIdx.x;
  if (bid < B * N) {
    const int row = bid;
    const int half = t >> 7, c = t & 127;
    __shared__ float xr[DN0];
    if (t < DN0) xr[t] = x[(size_t)row * DN0 + t];
    __syncthreads();
    float a = half ? 0.f : bm0[c];
    const float* wb = wm0 + half * DN0 * D;
    #pragma unroll 32
    for (int k = 0; k < DN0; ++k) a = fmaf(xr[k], wb[k * D + c], a);
    (half ? xj0 : xi0)[(size_t)row * D + c] = a;
  } else {
    const int g = (bid - B * N) * 256 + t;   // 0..32767
    const int layer = g >> 14;
    const int rem = g & 16383;               // = c*D + k
    const int c = rem >> 7, k = rem & 127;
    const float* src = layer ? wm2 : wm1;
    _Float16* dst = layer ? weT2 : weT1;
    dst[rem] = (_Float16)src[(2 * D + k) * D + c];
  }
}

// ---------------------------------------------------------------------------
// K2: layer-0 edge kernel. Unconditional msg0 stores (R19): masked rows are
// exact zeros, whole buffer defined. Exports agg0. Thread map matches k_fin:
// c8=(t&15)*8, jr=t>>4, j=16p+jr.
// ---------------------------------------------------------------------------
__global__ __launch_bounds__(256) void k_edge0(
    const int* __restrict__ ei, const float* __restrict__ eattr,
    const float* __restrict__ wm0,
    const float* __restrict__ xi0, const float* __restrict__ xj0,
    _Float16* __restrict__ msg0, float* __restrict__ agg0) {
  const int row = blockIdx.x;
  const int b = row >> 7;
  const int t = threadIdx.x;
  const int c8 = (t & 15) * 8, jr = t >> 4;

  __shared__ float eb[N * 20];          // e_row [j][k] pad 20; aliased by hp
  __shared__ float w_t[DE0][D];
  __shared__ float amask[N];
  __shared__ float xi_r[D];
  float* hp = eb;                       // [16][16][8] after matmul (8 KB)

  const float4* esrc = (const float4*)(eattr + (size_t)row * N * DE0);
  const float4* wsrc = (const float4*)(wm0 + 2 * DN0 * D);
  #pragma unroll
  for (int u = 0; u < 2; ++u) {
    const int idx4 = u * 256 + t;
    const int j = idx4 >> 2;
    const int k4 = (idx4 & 3) * 4;
    *(float4*)&eb[j * 20 + k4] = esrc[idx4];
    ((float4*)&w_t[0][0])[idx4] = wsrc[idx4];
  }
  if (t < N) {
    amask[t] = (float)ei[(size_t)row * N + t];
    xi_r[t] = xi0[(size_t)row * D + t];
  }
  __syncthreads();

  // --- K=16 matmul: acc[p][q] over j=16p+jr, c=c8+q ---
  float acc[8][8] = {};
  #pragma unroll 4
  for (int k = 0; k < DE0; ++k) {
    float av[8];
    #pragma unroll
    for (int p = 0; p < 8; ++p) av[p] = eb[(16 * p + jr) * 20 + k];
    const floatx4 wv0 = *(const floatx4*)&w_t[k][c8];
    const floatx4 wv1 = *(const floatx4*)&w_t[k][c8 + 4];
    #pragma unroll
    for (int p = 0; p < 8; ++p)
      #pragma unroll
      for (int q = 0; q < 4; ++q) {
        acc[p][q]     = fmaf(av[p], wv0[q], acc[p][q]);
        acc[p][4 + q] = fmaf(av[p], wv1[q], acc[p][4 + q]);
      }
  }

  // --- epilogue: relu+mask, half8 store (swizzled, ALL rows), agg ---
  float acc8[8] = {};
  const float* xjb = xj0 + (size_t)b * N * D;
  _Float16* mrow = msg0 + (size_t)row * N * D;
  const floatx4 xiv0 = *(const floatx4*)&xi_r[c8];
  const floatx4 xiv1 = *(const floatx4*)&xi_r[c8 + 4];
  #pragma unroll
  for (int p = 0; p < 8; ++p) {
    const int j = 16 * p + jr;
    const float am = amask[j];
    const floatx4 xjv0 = *(const floatx4*)&xjb[j * D + c8];
    const floatx4 xjv1 = *(const floatx4*)&xjb[j * D + c8 + 4];
    half8 hv;
    #pragma unroll
    for (int q = 0; q < 4; ++q) {
      float v0 = fmaxf(xiv0[q] + xjv0[q] + acc[p][q], 0.f) * am;
      float v1 = fmaxf(xiv1[q] + xjv1[q] + acc[p][4 + q], 0.f) * am;
      hv[q] = (_Float16)v0;
      hv[4 + q] = (_Float16)v1;
      acc8[q] += v0;
      acc8[4 + q] += v1;
    }
    *(half8*)&mrow[j * D + (((t & 15) ^ jr) << 3)] = hv;
  }

  __syncthreads();                      // eb reads done -> safe to alias hp
  #pragma unroll
  for (int q = 0; q < 8; ++q) hp[(jr * 16 + (t & 15)) * 8 + q] = acc8[q];
  __syncthreads();
  if (t < D) {
    float s = 0.f;
    #pragma unroll
    for (int g = 0; g < 16; ++g) s += hp[(g * 16 + (t >> 3)) * 8 + (t & 7)];
    agg0[(size_t)row * D + t] = s;
  }
}

// ---------------------------------------------------------------------------
// K3: batched node-0 + layer-1 projections. 4 rows/block (512 blocks).
//   x1  = relu(x0@Wx0 + agg0@Wa0 + bn0) ; xi1 = x1@Wi1+bm1 ; xj1 = x1@Wj1
// ---------------------------------------------------------------------------
__global__ __launch_bounds__(256) void k_node1(
    const float* __restrict__ x0, const float* __restrict__ agg0,
    const float* __restrict__ wn0, const float* __restrict__ bn0,
    const float* __restrict__ wm1, const float* __restrict__ bm1,
    float* __restrict__ x1, float* __restrict__ xi1, float* __restrict__ xj1) {
  const int r0 = blockIdx.x * 4;        // 512 blocks
  const int t = threadIdx.x;
  const int c = t & 127, rh = t >> 7;
  __shared__ float sIn[4][DN0];
  __shared__ float sAg[4][D];
  __shared__ float sX1[4][D];
  ((float*)sIn)[t] = x0[(size_t)r0 * DN0 + t];
  ((float2*)sAg)[t] = ((const float2*)(agg0 + (size_t)r0 * D))[t];
  __syncthreads();

  // node0: 2 rows per thread
  float acc[2];
  #pragma unroll
  for (int r = 0; r < 2; ++r) acc[r] = bn0[c];
  #pragma unroll 4
  for (int k4 = 0; k4 < DN0; k4 += 4) {
    const float* wb = wn0 + k4 * D + c;
    const float w0 = wb[0], w1 = wb[D], w2 = wb[2 * D], w3 = wb[3 * D];
    #pragma unroll
    for (int r = 0; r < 2; ++r) {
      const float4 xv = *(const float4*)&sIn[rh * 2 + r][k4];
      acc[r] = fmaf(xv.x, w0, acc[r]);
      acc[r] = fmaf(xv.y, w1, acc[r]);
      acc[r] = fmaf(xv.z, w2, acc[r]);
      acc[r] = fmaf(xv.w, w3, acc[r]);
    }
  }
  #pragma unroll 4
  for (int k4 = 0; k4 < D; k4 += 4) {
    const float* wb = wn0 + (DN0 + k4) * D + c;
    const float w0 = wb[0], w1 = wb[D], w2 = wb[2 * D], w3 = wb[3 * D];
    #pragma unroll
    for (int r = 0; r < 2; ++r) {
      const float4 xv = *(const float4*)&sAg[rh * 2 + r][k4];
      acc[r] = fmaf(xv.x, w0, acc[r]);
      acc[r] = fmaf(xv.y, w1, acc[r]);
      acc[r] = fmaf(xv.z, w2, acc[r]);
      acc[r] = fmaf(xv.w, w3, acc[r]);
    }
  }
  #pragma unroll
  for (int r = 0; r < 2; ++r) {
    const float v = fmaxf(acc[r], 0.f);
    sX1[rh * 2 + r][c] = v;
    x1[(size_t)(r0 + rh * 2 + r) * D + c] = v;
  }
  __syncthreads();

  // xi1 (rh=0, +bm1) / xj1 (rh=1): 4 rows per thread
  float a[4];
  #pragma unroll
  for (int r = 0; r < 4; ++r) a[r] = rh ? 0.f : bm1[c];
  const float* wh = wm1 + (size_t)rh * D * D;
  #pragma unroll 4
  for (int k4 = 0; k4 < D; k4 += 4) {
    const float* wb = wh + k4 * D + c;
    const float w0 = wb[0], w1 = wb[D], w2 = wb[2 * D], w3 = wb[3 * D];
    #pragma unroll
    for (int r = 0; r < 4; ++r) {
      const float4 xv = *(const float4*)&sX1[r][k4];
      a[r] = fmaf(xv.x, w0, a[r]);
      a[r] = fmaf(xv.y, w1, a[r]);
      a[r] = fmaf(xv.z, w2, a[r]);
      a[r] = fmaf(xv.w, w3, a[r]);
    }
  }
  float* dst = rh ? xj1 : xi1;
  #pragma unroll
  for (int r = 0; r < 4; ++r) dst[(size_t)(r0 + r) * D + c] = a[r];
}

// ---------------------------------------------------------------------------
// K4: fused layer-1+2 edge kernel. R20: 8-WAVE SPLIT (512 thr) — occupancy
// was reg-capped at 2 blocks/CU (76 VGPR + 64 AGPR acc > 128-reg step, m69).
// Wave (w=wv&3, jh=wv>>2) owns c-tile [32w,32w+32) x j-half [64jh,64jh+64):
// acc 64->32 AGPR, peak regs ~95 < 128 -> launch_bounds(512,4) = 16 waves/CU.
// Per-block MFMA total unchanged (intra-block split, NOT the R18 block
// split). agg1: per-wave butterfly covers 64 j -> partials combined in LDS
// sAggP[2][128] using existing barriers. C/D layout (m74/m101):
// col(j)=lane&31, row(c)=(reg&3)+8*(reg>>2)+4*(lane>>5).
// ---------------------------------------------------------------------------
__global__ __launch_bounds__(512, 4) void k_mid(
    const int* __restrict__ ei, const _Float16* __restrict__ weT1,
    const _Float16* __restrict__ weT2,
    const float* __restrict__ xi, const float* __restrict__ xj,
    _Float16* __restrict__ em,          // in: msg0 (swizzled), out: T2
    float* __restrict__ agg1) {
  const int row = blockIdx.x;           // 2048
  const int b = row >> 7;
  const int t = threadIdx.x;            // 0..511
  const int wv = t >> 6;                // 0..7
  const int w = wv & 3;                 // c-tile base 32w
  const int jh = wv >> 2;               // j-half base 64jh
  const int lane = t & 63;
  const int l31 = lane & 31;
  const int l15 = lane & 15;
  const int hl = lane >> 5;             // k-half; c offset 4*hl

  __shared__ _Float16 sE[N * D];        // 32 KB, swizzled rows
  __shared__ float sMask[N];
  __shared__ float sAggP[2][N];         // agg1 j-half partials

  // --- async-stage msg0 row (linear copy of swizzled layout) ---
  const _Float16* gsrc = em + (size_t)row * N * D;
  #pragma unroll
  for (int u = 0; u < 4; ++u) {
    const int seg = (u * 8 + wv) * 512; // wave-uniform base, 1 KB per instr
    gld16(gsrc + seg + lane * 8, &sE[seg]);
  }

  // --- pass-1 weight frags: A[m=l31][k=16ks+8hl+e] ---
  half8 a1[8];
  #pragma unroll
  for (int ks = 0; ks < 8; ++ks)
    a1[ks] = *(const half8*)(weT1 + (32 * w + l31) * D + 16 * ks + 8 * hl);

  // --- per-lane invariants (overlap staging) ---
  floatx4 xiv[4];
  #pragma unroll
  for (int g = 0; g < 4; ++g)
    xiv[g] = *(const floatx4*)&xi[(size_t)row * D + 32 * w + 8 * g + 4 * hl];
  if (t < N) sMask[t] = (float)ei[(size_t)row * N + t];

  __syncthreads();                      // drains gld16; sMask visible

  float am[2];
  #pragma unroll
  for (int jt = 0; jt < 2; ++jt) am[jt] = sMask[64 * jh + 32 * jt + l31];

  // --- pass 1: T1[c][j] = sum_k We1T[c][k] msg0[j][k] ---
  const floatx16 vzero = {0.f,0.f,0.f,0.f,0.f,0.f,0.f,0.f,
                          0.f,0.f,0.f,0.f,0.f,0.f,0.f,0.f};
  floatx16 acc[2];
  #pragma unroll
  for (int jt = 0; jt < 2; ++jt) acc[jt] = vzero;
  #pragma unroll
  for (int ks = 0; ks < 8; ++ks)
    #pragma unroll
    for (int jt = 0; jt < 2; ++jt) {
      const half8 bv = *(const half8*)
          &sE[(64 * jh + 32 * jt + l31) * D + (((2 * ks + hl) ^ l15) << 3)];
      acc[jt] = __builtin_amdgcn_mfma_f32_32x32x16_f16(a1[ks], bv, acc[jt], 0, 0, 0);
    }

  __syncthreads();                      // all pass-1 reads complete

  // --- epilogue 1: msg1 -> hacc, e_mid RMW in LDS ---
  const float* xjb = xj + (size_t)b * N * D;
  floatx4 hacc[4];
  #pragma unroll
  for (int g = 0; g < 4; ++g) hacc[g] = (floatx4){0.f, 0.f, 0.f, 0.f};
  #pragma unroll
  for (int jt = 0; jt < 2; ++jt) {
    const int j = 64 * jh + 32 * jt + l31;   // j&15 == l15
    #pragma unroll
    for (int g = 0; g < 4; ++g) {
      const int cofs = 32 * w + 8 * g + 4 * hl;
      const int hidx = j * D + (((4 * w + g) ^ l15) << 3) + 4 * hl;
      const floatx4 xjv = *(const floatx4*)&xjb[j * D + cofs];
      const half4 m0 = *(const half4*)&sE[hidx];
      half4 mid;
      floatx4 m1;
      #pragma unroll
      for (int r = 0; r < 4; ++r) {
        const float v = xiv[g][r] + xjv[r] + acc[jt][4 * g + r];
        m1[r] = fmaxf(v, 0.f) * am[jt];
        mid[r] = (_Float16)(0.5f * ((float)m0[r] + m1[r]));
      }
      *(half4*)&sE[hidx] = mid;
      hacc[g] += m1;
    }
  }

  // agg1 partial: butterfly over l31 spans this wave's 64 j; park in LDS
  #pragma unroll
  for (int m = 1; m < 32; m <<= 1)
    #pragma unroll
    for (int g = 0; g < 4; ++g)
      #pragma unroll
      for (int r = 0; r < 4; ++r)
        hacc[g][r] += __shfl_xor(hacc[g][r], m, 64);
  if (l31 == 0) {
    #pragma unroll
    for (int g = 0; g < 4; ++g)
      *(floatx4*)&sAggP[jh][32 * w + 8 * g + 4 * hl] = hacc[g];
  }

  // pass-2 weights (a1 dead -> regs reusable)
  half8 a2[8];
  #pragma unroll
  for (int ks = 0; ks < 8; ++ks)
    a2[ks] = *(const half8*)(weT2 + (32 * w + l31) * D + 16 * ks + 8 * hl);

  __syncthreads();                      // e_mid + sAggP visible to all waves

  // --- pass 2: T2[c][j] = sum_k We2T[c][k] e_mid[j][k] ---
  #pragma unroll
  for (int jt = 0; jt < 2; ++jt) acc[jt] = vzero;
  #pragma unroll
  for (int ks = 0; ks < 8; ++ks)
    #pragma unroll
    for (int jt = 0; jt < 2; ++jt) {
      const half8 bv = *(const half8*)
          &sE[(64 * jh + 32 * jt + l31) * D + (((2 * ks + hl) ^ l15) << 3)];
      acc[jt] = __builtin_amdgcn_mfma_f32_32x32x16_f16(a2[ks], bv, acc[jt], 0, 0, 0);
    }

  __syncthreads();                      // all pass-2 reads complete

  // --- agg1 finalize (sAggP stable since pre-pass-2 barrier) ---
  if (t < N) agg1[(size_t)row * D + t] = sAggP[0][t] + sAggP[1][t];

  // --- deposit T2 into sE (same cell mapping) ---
  #pragma unroll
  for (int jt = 0; jt < 2; ++jt) {
    const int j = 64 * jh + 32 * jt + l31;
    #pragma unroll
    for (int g = 0; g < 4; ++g) {
      const int hidx = j * D + (((4 * w + g) ^ l15) << 3) + 4 * hl;
      half4 tv;
      #pragma unroll
      for (int r = 0; r < 4; ++r) tv[r] = (_Float16)acc[jt][4 * g + r];
      *(half4*)&sE[hidx] = tv;
    }
  }

  __syncthreads();                      // T2 complete in LDS

  // --- copy-out, unmasked j rows only (swizzled layout preserved) ---
  uint4* gdst = (uint4*)(em + (size_t)row * N * D);
  const uint4* ls = (const uint4*)sE;
  #pragma unroll
  for (int u = 0; u < 4; ++u) {
    const int idx4 = u * 512 + t;       // 2048 16B cells
    const int j = idx4 >> 4;
    if (sMask[j] != 0.f) gdst[idx4] = ls[idx4];
  }
}

// ---------------------------------------------------------------------------
// K5: batched node-1 + layer-2 projections. 4 rows/block (512 blocks).
//   x_mid = 0.5*(x1 + relu(x1@Wx1 + agg1@Wa1 + bn1))   (LDS only)
//   xi2 = x_mid@Wi2 + bm2 ;  xj2 = x_mid@Wj2
// ---------------------------------------------------------------------------
__global__ __launch_bounds__(256) void k_node2(
    const float* __restrict__ x1, const float* __restrict__ agg1,
    const float* __restrict__ wn1, const float* __restrict__ bn1,
    const float* __restrict__ wm2, const float* __restrict__ bm2,
    float* __restrict__ xi2, float* __restrict__ xj2) {
  const int r0 = blockIdx.x * 4;        // 512 blocks
  const int t = threadIdx.x;
  const int c = t & 127, rh = t >> 7;
  __shared__ float sIn[4][D];
  __shared__ float sAg[4][D];
  __shared__ float sXm[4][D];
  ((float2*)sIn)[t] = ((const float2*)(x1 + (size_t)r0 * D))[t];
  ((float2*)sAg)[t] = ((const float2*)(agg1 + (size_t)r0 * D))[t];
  __syncthreads();

  float acc[2];
  #pragma unroll
  for (int r = 0; r < 2; ++r) acc[r] = bn1[c];
  #pragma unroll 4
  for (int k4 = 0; k4 < D; k4 += 4) {
    const float* wb = wn1 + k4 * D + c;
    const float w0 = wb[0], w1 = wb[D], w2 = wb[2 * D], w3 = wb[3 * D];
    #pragma unroll
    for (int r = 0; r < 2; ++r) {
      const float4 xv = *(const float4*)&sIn[rh * 2 + r][k4];
      acc[r] = fmaf(xv.x, w0, acc[r]);
      acc[r] = fmaf(xv.y, w1, acc[r]);
      acc[r] = fmaf(xv.z, w2, acc[r]);
      acc[r] = fmaf(xv.w, w3, acc[r]);
    }
  }
  #pragma unroll 4
  for (int k4 = 0; k4 < D; k4 += 4) {
    const float* wb = wn1 + (D + k4) * D + c;
    const float w0 = wb[0], w1 = wb[D], w2 = wb[2 * D], w3 = wb[3 * D];
    #pragma unroll
    for (int r = 0; r < 2; ++r) {
      const float4 xv = *(const float4*)&sAg[rh * 2 + r][k4];
      acc[r] = fmaf(xv.x, w0, acc[r]);
      acc[r] = fmaf(xv.y, w1, acc[r]);
      acc[r] = fmaf(xv.z, w2, acc[r]);
      acc[r] = fmaf(xv.w, w3, acc[r]);
    }
  }
  #pragma unroll
  for (int r = 0; r < 2; ++r) {
    const float v = 0.5f * (sIn[rh * 2 + r][c] + fmaxf(acc[r], 0.f));
    sXm[rh * 2 + r][c] = v;
  }
  __syncthreads();

  float a[4];
  #pragma unroll
  for (int r = 0; r < 4; ++r) a[r] = rh ? 0.f : bm2[c];
  const float* wh = wm2 + (size_t)rh * D * D;
  #pragma unroll 4
  for (int k4 = 0; k4 < D; k4 += 4) {
    const float* wb = wh + k4 * D + c;
    const float w0 = wb[0], w1 = wb[D], w2 = wb[2 * D], w3 = wb[3 * D];
    #pragma unroll
    for (int r = 0; r < 4; ++r) {
      const float4 xv = *(const float4*)&sXm[r][k4];
      a[r] = fmaf(xv.x, w0, a[r]);
      a[r] = fmaf(xv.y, w1, a[r]);
      a[r] = fmaf(xv.z, w2, a[r]);
      a[r] = fmaf(xv.w, w3, a[r]);
    }
  }
  float* dst = rh ? xj2 : xi2;
  #pragma unroll
  for (int r = 0; r < 4; ++r) dst[(size_t)(r0 + r) * D + c] = a[r];
}

// ---------------------------------------------------------------------------
// K6: final layer streaming: msg2 = relu(xi2 + xj2 + T2)*A; rowsum over j.
// Masked j rows skipped entirely (contribution 0; saves their 256 B loads).
// ---------------------------------------------------------------------------
__global__ __launch_bounds__(256) void k_fin(
    const int* __restrict__ ei, const _Float16* __restrict__ t2,
    const float* __restrict__ xi, const float* __restrict__ xj,
    float* __restrict__ rowsum) {
  const int row = blockIdx.x;
  const int b = row >> 7;
  const int t = threadIdx.x;
  const int c8 = (t & 15) * 8, jr = t >> 4;

  __shared__ float sMask[N];
  __shared__ float hp[16][16][8];
  if (t < N) sMask[t] = (float)ei[(size_t)row * N + t];
  float xiv[8];
  *(floatx4*)&xiv[0] = *(const floatx4*)&xi[row * D + c8];
  *(floatx4*)&xiv[4] = *(const floatx4*)&xi[row * D + c8 + 4];
  __syncthreads();

  const _Float16* src = t2 + (size_t)row * N * D;
  const float* xjb = xj + (size_t)b * N * D;
  float acc8[8] = {};
  #pragma unroll
  for (int u = 0; u < 8; ++u) {
    const int j = u * 16 + jr;           // j&15 == jr
    if (sMask[j] != 0.f) {
      const half8 tv = *(const half8*)(src + j * D + (((t & 15) ^ jr) << 3));
      const floatx4 xj0 = *(const floatx4*)&xjb[j * D + c8];
      const floatx4 xj1 = *(const floatx4*)&xjb[j * D + c8 + 4];
      #pragma unroll
      for (int r = 0; r < 4; ++r) {
        acc8[r]     += fmaxf(xiv[r] + xj0[r] + (float)tv[r], 0.f);
        acc8[4 + r] += fmaxf(xiv[4 + r] + xj1[r] + (float)tv[4 + r], 0.f);
      }
    }
  }
  #pragma unroll
  for (int k = 0; k < 8; ++k) hp[jr][t & 15][k] = acc8[k];
  __syncthreads();
  if (t < D) {
    float s = 0.f;
    #pragma unroll
    for (int g = 0; g < 16; ++g) s += hp[g][t >> 3][t & 7];
    rowsum[row * D + t] = s;
  }
}

// ---------------------------------------------------------------------------
// K7: head MLP. 16 blocks.
// ---------------------------------------------------------------------------
__global__ __launch_bounds__(128) void k_head(
    const float* __restrict__ rowsum,
    const float* __restrict__ w1, const float* __restrict__ b1,
    const float* __restrict__ w2, const float* __restrict__ b2,
    const float* __restrict__ w3, const float* __restrict__ b3,
    float* __restrict__ out) {
  const int b = blockIdx.x;
  const int c = threadIdx.x;
  __shared__ float hr[D], h1r[D], h2r[D];
  const float* rs = rowsum + (size_t)b * N * D;
  float s = 0.f;
  for (int i = 0; i < N; ++i) s += rs[i * D + c];
  hr[c] = s * (1.f / (N * N));
  __syncthreads();
  float a = b1[c];
  #pragma unroll 8
  for (int k = 0; k < D; ++k) a = fmaf(hr[k], w1[k * D + c], a);
  h1r[c] = fmaxf(a, 0.f);
  __syncthreads();
  a = b2[c];
  #pragma unroll 8
  for (int k = 0; k < D; ++k) a = fmaf(h1r[k], w2[k * D + c], a);
  h2r[c] = fmaxf(a, 0.f);
  __syncthreads();
  hr[c] = h2r[c] * w3[c];
  __syncthreads();
  if (c == 0) {
    float s2 = b3[0];
    for (int k = 0; k < D; ++k) s2 += hr[k];
    out[b] = s2;
  }
}

// ---------------------------------------------------------------------------
extern "C" void kernel_launch(void* const* d_in, const int* in_sizes, int n_in,
                              void* d_out, int out_size, void* d_ws, size_t ws_size,
                              hipStream_t stream) {
  const int*   ei  = (const int*)d_in[0];
  const float* x0  = (const float*)d_in[1];
  const float* ea  = (const float*)d_in[2];
  const float* wm0 = (const float*)d_in[3];
  const float* bm0 = (const float*)d_in[4];
  const float* wn0 = (const float*)d_in[5];
  const float* bn0 = (const float*)d_in[6];
  const float* wm1 = (const float*)d_in[7];
  const float* bm1 = (const float*)d_in[8];
  const float* wn1 = (const float*)d_in[9];
  const float* bn1 = (const float*)d_in[10];
  const float* wm2 = (const float*)d_in[11];
  const float* bm2 = (const float*)d_in[12];
  const float* wh1 = (const float*)d_in[15];
  const float* bh1 = (const float*)d_in[16];
  const float* wh2 = (const float*)d_in[17];
  const float* bh2 = (const float*)d_in[18];
  const float* wh3 = (const float*)d_in[19];
  const float* bh3 = (const float*)d_in[20];
  float* out = (float*)d_out;

  _Float16* msg0h = (_Float16*)d_ws;                 // [B,N,N,D] fp16: msg0 -> T2
  _Float16* weT1  = msg0h + (size_t)B * N * N * D;
  _Float16* weT2  = weT1 + D * D;
  float* f = (float*)(weT2 + D * D);
  size_t off = 0;
  const size_t R = (size_t)B * N * D;
  float* xi0  = f + off; off += R;
  float* xj0  = f + off; off += R;
  float* x1   = f + off; off += R;
  float* xi1  = f + off; off += R;
  float* xj1  = f + off; off += R;
  float* xi2  = f + off; off += R;
  float* xj2  = f + off; off += R;
  float* rsum = f + off; off += R;

  // agg scratch: rsum buffer is dead until k_fin, so it carries agg0
  // (k_edge0 -> k_node1) and then agg1 (k_mid -> k_node2). Stream order
  // guarantees each consumer reads before the next producer overwrites.
  float* aggS = rsum;

  const int rows = B * N;   // 2048
  k_pre  <<<rows + 128, 256, 0, stream>>>(x0, wm0, bm0, wm1, wm2,
                                          xi0, xj0, weT1, weT2);
  k_edge0<<<rows, 256, 0, stream>>>(ei, ea, wm0, xi0, xj0, msg0h, aggS);
  k_node1<<<rows / 4, 256, 0, stream>>>(x0, aggS, wn0, bn0, wm1, bm1,
                                        x1, xi1, xj1);
  k_mid  <<<rows, 512, 0, stream>>>(ei, weT1, weT2, xi1, xj1, msg0h, aggS);
  k_node2<<<rows / 4, 256, 0, stream>>>(x1, aggS, wn1, bn1, wm2, bm2,
                                        xi2, xj2);
  k_fin  <<<rows, 256, 0, stream>>>(ei, msg0h, xi2, xj2, rsum);
  k_head <<<B,    128, 0, stream>>>(rsum, wh1, bh1, wh2, bh2, wh3, bh3, out);
}

// Round 6
// 217.265 us; speedup vs baseline: 1.0484x; 1.0484x over previous
//
#include <hip/hip_runtime.h>

constexpr int B = 16, N = 128, D = 128, DN0 = 64, DE0 = 16;

typedef _Float16 half8 __attribute__((ext_vector_type(8)));
typedef _Float16 half4 __attribute__((ext_vector_type(4)));
typedef float floatx4 __attribute__((ext_vector_type(4)));
typedef float floatx16 __attribute__((ext_vector_type(16)));

// async 16B global->LDS. msg0/T2 global layout is cell-swizzled
// (16B cell g of row j stored at g^(j&15)) so linear copies land
// conflict-free in LDS.
__device__ __forceinline__ void gld16(const _Float16* g, _Float16* l) {
  __builtin_amdgcn_global_load_lds(
      (const __attribute__((address_space(1))) void*)g,
      (__attribute__((address_space(3))) void*)l, 16, 0, 0);
}

// ---------------------------------------------------------------------------
// K1: merged prep. R21: xi0/xj0 part BATCHED 4 rows/block (512 blocks) —
// the per-row version re-streamed 32 KB of wm0 per row (2048x redundant,
// k_node1-pattern fix). bid >= 512 (128 blocks): WeT transposes.
// Weights stay k-major (R15: wave-coalesced).
// ---------------------------------------------------------------------------
__global__ __launch_bounds__(256) void k_pre(
    const float* __restrict__ x, const float* __restrict__ wm0,
    const float* __restrict__ bm0, const float* __restrict__ wm1,
    const float* __restrict__ wm2,
    float* __restrict__ xi0, float* __restrict__ xj0,
    _Float16* __restrict__ weT1, _Float16* __restrict__ weT2) {
  const int bid = blockIdx.x;
  const int t = threadIdx.x;
  if (bid < 512) {
    const int r0 = bid * 4;
    const int half = t >> 7, c = t & 127;
    __shared__ float sX[4][DN0];
    ((float*)sX)[t] = x[(size_t)r0 * DN0 + t];
    __syncthreads();
    float acc[4];
    #pragma unroll
    for (int r = 0; r < 4; ++r) acc[r] = half ? 0.f : bm0[c];
    const float* wb0 = wm0 + half * DN0 * D;
    #pragma unroll 4
    for (int k4 = 0; k4 < DN0; k4 += 4) {
      const float* wb = wb0 + k4 * D + c;
      const float w0 = wb[0], w1 = wb[D], w2 = wb[2 * D], w3 = wb[3 * D];
      #pragma unroll
      for (int r = 0; r < 4; ++r) {
        const float4 xv = *(const float4*)&sX[r][k4];
        acc[r] = fmaf(xv.x, w0, acc[r]);
        acc[r] = fmaf(xv.y, w1, acc[r]);
        acc[r] = fmaf(xv.z, w2, acc[r]);
        acc[r] = fmaf(xv.w, w3, acc[r]);
      }
    }
    float* dst = half ? xj0 : xi0;
    #pragma unroll
    for (int r = 0; r < 4; ++r) dst[(size_t)(r0 + r) * D + c] = acc[r];
  } else {
    const int g = (bid - 512) * 256 + t;     // 0..32767
    const int layer = g >> 14;
    const int rem = g & 16383;               // = c*D + k
    const int c = rem >> 7, k = rem & 127;
    const float* src = layer ? wm2 : wm1;
    _Float16* dst = layer ? weT2 : weT1;
    dst[rem] = (_Float16)src[(2 * D + k) * D + c];
  }
}

// ---------------------------------------------------------------------------
// K2: layer-0 edge kernel. Unconditional msg0 stores (R19): masked rows are
// exact zeros, whole buffer defined. Exports agg0. Thread map matches k_fin:
// c8=(t&15)*8, jr=t>>4, j=16p+jr.
// ---------------------------------------------------------------------------
__global__ __launch_bounds__(256) void k_edge0(
    const int* __restrict__ ei, const float* __restrict__ eattr,
    const float* __restrict__ wm0,
    const float* __restrict__ xi0, const float* __restrict__ xj0,
    _Float16* __restrict__ msg0, float* __restrict__ agg0) {
  const int row = blockIdx.x;
  const int b = row >> 7;
  const int t = threadIdx.x;
  const int c8 = (t & 15) * 8, jr = t >> 4;

  __shared__ float eb[N * 20];          // e_row [j][k] pad 20; aliased by hp
  __shared__ float w_t[DE0][D];
  __shared__ float amask[N];
  __shared__ float xi_r[D];
  float* hp = eb;                       // [16][16][8] after matmul (8 KB)

  const float4* esrc = (const float4*)(eattr + (size_t)row * N * DE0);
  const float4* wsrc = (const float4*)(wm0 + 2 * DN0 * D);
  #pragma unroll
  for (int u = 0; u < 2; ++u) {
    const int idx4 = u * 256 + t;
    const int j = idx4 >> 2;
    const int k4 = (idx4 & 3) * 4;
    *(float4*)&eb[j * 20 + k4] = esrc[idx4];
    ((float4*)&w_t[0][0])[idx4] = wsrc[idx4];
  }
  if (t < N) {
    amask[t] = (float)ei[(size_t)row * N + t];
    xi_r[t] = xi0[(size_t)row * D + t];
  }
  __syncthreads();

  // --- K=16 matmul: acc[p][q] over j=16p+jr, c=c8+q ---
  float acc[8][8] = {};
  #pragma unroll 4
  for (int k = 0; k < DE0; ++k) {
    float av[8];
    #pragma unroll
    for (int p = 0; p < 8; ++p) av[p] = eb[(16 * p + jr) * 20 + k];
    const floatx4 wv0 = *(const floatx4*)&w_t[k][c8];
    const floatx4 wv1 = *(const floatx4*)&w_t[k][c8 + 4];
    #pragma unroll
    for (int p = 0; p < 8; ++p)
      #pragma unroll
      for (int q = 0; q < 4; ++q) {
        acc[p][q]     = fmaf(av[p], wv0[q], acc[p][q]);
        acc[p][4 + q] = fmaf(av[p], wv1[q], acc[p][4 + q]);
      }
  }

  // --- epilogue: relu+mask, half8 store (swizzled, ALL rows), agg ---
  float acc8[8] = {};
  const float* xjb = xj0 + (size_t)b * N * D;
  _Float16* mrow = msg0 + (size_t)row * N * D;
  const floatx4 xiv0 = *(const floatx4*)&xi_r[c8];
  const floatx4 xiv1 = *(const floatx4*)&xi_r[c8 + 4];
  #pragma unroll
  for (int p = 0; p < 8; ++p) {
    const int j = 16 * p + jr;
    const float am = amask[j];
    const floatx4 xjv0 = *(const floatx4*)&xjb[j * D + c8];
    const floatx4 xjv1 = *(const floatx4*)&xjb[j * D + c8 + 4];
    half8 hv;
    #pragma unroll
    for (int q = 0; q < 4; ++q) {
      float v0 = fmaxf(xiv0[q] + xjv0[q] + acc[p][q], 0.f) * am;
      float v1 = fmaxf(xiv1[q] + xjv1[q] + acc[p][4 + q], 0.f) * am;
      hv[q] = (_Float16)v0;
      hv[4 + q] = (_Float16)v1;
      acc8[q] += v0;
      acc8[4 + q] += v1;
    }
    *(half8*)&mrow[j * D + (((t & 15) ^ jr) << 3)] = hv;
  }

  __syncthreads();                      // eb reads done -> safe to alias hp
  #pragma unroll
  for (int q = 0; q < 8; ++q) hp[(jr * 16 + (t & 15)) * 8 + q] = acc8[q];
  __syncthreads();
  if (t < D) {
    float s = 0.f;
    #pragma unroll
    for (int g = 0; g < 16; ++g) s += hp[(g * 16 + (t >> 3)) * 8 + (t & 7)];
    agg0[(size_t)row * D + t] = s;
  }
}

// ---------------------------------------------------------------------------
// K3: batched node-0 + layer-1 projections. 4 rows/block (512 blocks).
//   x1  = relu(x0@Wx0 + agg0@Wa0 + bn0) ; xi1 = x1@Wi1+bm1 ; xj1 = x1@Wj1
// ---------------------------------------------------------------------------
__global__ __launch_bounds__(256) void k_node1(
    const float* __restrict__ x0, const float* __restrict__ agg0,
    const float* __restrict__ wn0, const float* __restrict__ bn0,
    const float* __restrict__ wm1, const float* __restrict__ bm1,
    float* __restrict__ x1, float* __restrict__ xi1, float* __restrict__ xj1) {
  const int r0 = blockIdx.x * 4;        // 512 blocks
  const int t = threadIdx.x;
  const int c = t & 127, rh = t >> 7;
  __shared__ float sIn[4][DN0];
  __shared__ float sAg[4][D];
  __shared__ float sX1[4][D];
  ((float*)sIn)[t] = x0[(size_t)r0 * DN0 + t];
  ((float2*)sAg)[t] = ((const float2*)(agg0 + (size_t)r0 * D))[t];
  __syncthreads();

  // node0: 2 rows per thread
  float acc[2];
  #pragma unroll
  for (int r = 0; r < 2; ++r) acc[r] = bn0[c];
  #pragma unroll 4
  for (int k4 = 0; k4 < DN0; k4 += 4) {
    const float* wb = wn0 + k4 * D + c;
    const float w0 = wb[0], w1 = wb[D], w2 = wb[2 * D], w3 = wb[3 * D];
    #pragma unroll
    for (int r = 0; r < 2; ++r) {
      const float4 xv = *(const float4*)&sIn[rh * 2 + r][k4];
      acc[r] = fmaf(xv.x, w0, acc[r]);
      acc[r] = fmaf(xv.y, w1, acc[r]);
      acc[r] = fmaf(xv.z, w2, acc[r]);
      acc[r] = fmaf(xv.w, w3, acc[r]);
    }
  }
  #pragma unroll 4
  for (int k4 = 0; k4 < D; k4 += 4) {
    const float* wb = wn0 + (DN0 + k4) * D + c;
    const float w0 = wb[0], w1 = wb[D], w2 = wb[2 * D], w3 = wb[3 * D];
    #pragma unroll
    for (int r = 0; r < 2; ++r) {
      const float4 xv = *(const float4*)&sAg[rh * 2 + r][k4];
      acc[r] = fmaf(xv.x, w0, acc[r]);
      acc[r] = fmaf(xv.y, w1, acc[r]);
      acc[r] = fmaf(xv.z, w2, acc[r]);
      acc[r] = fmaf(xv.w, w3, acc[r]);
    }
  }
  #pragma unroll
  for (int r = 0; r < 2; ++r) {
    const float v = fmaxf(acc[r], 0.f);
    sX1[rh * 2 + r][c] = v;
    x1[(size_t)(r0 + rh * 2 + r) * D + c] = v;
  }
  __syncthreads();

  // xi1 (rh=0, +bm1) / xj1 (rh=1): 4 rows per thread
  float a[4];
  #pragma unroll
  for (int r = 0; r < 4; ++r) a[r] = rh ? 0.f : bm1[c];
  const float* wh = wm1 + (size_t)rh * D * D;
  #pragma unroll 4
  for (int k4 = 0; k4 < D; k4 += 4) {
    const float* wb = wh + k4 * D + c;
    const float w0 = wb[0], w1 = wb[D], w2 = wb[2 * D], w3 = wb[3 * D];
    #pragma unroll
    for (int r = 0; r < 4; ++r) {
      const float4 xv = *(const float4*)&sX1[r][k4];
      a[r] = fmaf(xv.x, w0, a[r]);
      a[r] = fmaf(xv.y, w1, a[r]);
      a[r] = fmaf(xv.z, w2, a[r]);
      a[r] = fmaf(xv.w, w3, a[r]);
    }
  }
  float* dst = rh ? xj1 : xi1;
  #pragma unroll
  for (int r = 0; r < 4; ++r) dst[(size_t)(r0 + r) * D + c] = a[r];
}

// ---------------------------------------------------------------------------
// K4: fused layer-1+2 edge kernel. R21: back to the R19-best shape (256 thr,
// 4 waves, full row, 2 blocks/CU — both R18 block-split and R20 wave-split
// regressed) + xj PREFETCH: the epilogue's 16 floatx4 L2 loads are issued
// BEFORE the first barrier (static indices, rule #20) so their latency hides
// under the gld16 staging instead of sitting serially after pass 1.
// C/D layout (m74/m101): col(j)=lane&31, row(c)=(reg&3)+8*(reg>>2)+4*(lane>>5).
// ---------------------------------------------------------------------------
__global__ __launch_bounds__(256, 2) void k_mid(
    const int* __restrict__ ei, const _Float16* __restrict__ weT1,
    const _Float16* __restrict__ weT2,
    const float* __restrict__ xi, const float* __restrict__ xj,
    _Float16* __restrict__ em,          // in: msg0 (swizzled), out: T2
    float* __restrict__ agg1) {
  const int row = blockIdx.x;           // 2048
  const int b = row >> 7;
  const int t = threadIdx.x;
  const int w = t >> 6;                 // c-tile base 32w
  const int lane = t & 63;
  const int l31 = lane & 31;
  const int l15 = lane & 15;
  const int hl = lane >> 5;             // k-half; c offset 4*hl

  __shared__ _Float16 sE[N * D];        // 32 KB, swizzled rows
  __shared__ float sMask[N];

  // --- async-stage msg0 row (linear copy of swizzled layout) ---
  const _Float16* gsrc = em + (size_t)row * N * D;
  #pragma unroll
  for (int u = 0; u < 8; ++u) {
    const int seg = (u * 4 + w) * 512;  // wave-uniform base, 1 KB per instr
    gld16(gsrc + seg + lane * 8, &sE[seg]);
  }

  // --- pass-1 weight frags: A[m=l31][k=16ks+8hl+e] ---
  half8 a1[8];
  #pragma unroll
  for (int ks = 0; ks < 8; ++ks)
    a1[ks] = *(const half8*)(weT1 + (32 * w + l31) * D + 16 * ks + 8 * hl);

  // --- per-lane invariants + xj prefetch (overlap staging latency) ---
  floatx4 xiv[4];
  #pragma unroll
  for (int g = 0; g < 4; ++g)
    xiv[g] = *(const floatx4*)&xi[(size_t)row * D + 32 * w + 8 * g + 4 * hl];
  const float* xjb = xj + (size_t)b * N * D;
  floatx4 xjp[16];                      // [jt*4+g], static idx only
  #pragma unroll
  for (int jt = 0; jt < 4; ++jt)
    #pragma unroll
    for (int g = 0; g < 4; ++g)
      xjp[jt * 4 + g] = *(const floatx4*)
          &xjb[(32 * jt + l31) * D + 32 * w + 8 * g + 4 * hl];
  if (t < N) sMask[t] = (float)ei[(size_t)row * N + t];

  __syncthreads();                      // drains gld16; sMask visible

  float am[4];
  #pragma unroll
  for (int jt = 0; jt < 4; ++jt) am[jt] = sMask[32 * jt + l31];

  // --- pass 1: T1[c][j] = sum_k We1T[c][k] msg0[j][k] ---
  const floatx16 vzero = {0.f,0.f,0.f,0.f,0.f,0.f,0.f,0.f,
                          0.f,0.f,0.f,0.f,0.f,0.f,0.f,0.f};
  floatx16 acc[4];
  #pragma unroll
  for (int jt = 0; jt < 4; ++jt) acc[jt] = vzero;
  #pragma unroll
  for (int ks = 0; ks < 8; ++ks)
    #pragma unroll
    for (int jt = 0; jt < 4; ++jt) {
      const half8 bv = *(const half8*)
          &sE[(32 * jt + l31) * D + (((2 * ks + hl) ^ l15) << 3)];
      acc[jt] = __builtin_amdgcn_mfma_f32_32x32x16_f16(a1[ks], bv, acc[jt], 0, 0, 0);
    }

  __syncthreads();                      // all pass-1 reads complete

  // --- epilogue 1: msg1 -> hacc, e_mid RMW in LDS ---
  floatx4 hacc[4];
  #pragma unroll
  for (int g = 0; g < 4; ++g) hacc[g] = (floatx4){0.f, 0.f, 0.f, 0.f};
  #pragma unroll
  for (int jt = 0; jt < 4; ++jt) {
    const int j = 32 * jt + l31;        // j&15 == l15
    #pragma unroll
    for (int g = 0; g < 4; ++g) {
      const int hidx = j * D + (((4 * w + g) ^ l15) << 3) + 4 * hl;
      const floatx4 xjv = xjp[jt * 4 + g];
      const half4 m0 = *(const half4*)&sE[hidx];
      half4 mid;
      floatx4 m1;
      #pragma unroll
      for (int r = 0; r < 4; ++r) {
        const float v = xiv[g][r] + xjv[r] + acc[jt][4 * g + r];
        m1[r] = fmaxf(v, 0.f) * am[jt];
        mid[r] = (_Float16)(0.5f * ((float)m0[r] + m1[r]));
      }
      *(half4*)&sE[hidx] = mid;
      hacc[g] += m1;
    }
  }

  // agg1: butterfly over l31 spans all 128 j; export direct to global
  #pragma unroll
  for (int m = 1; m < 32; m <<= 1)
    #pragma unroll
    for (int g = 0; g < 4; ++g)
      #pragma unroll
      for (int r = 0; r < 4; ++r)
        hacc[g][r] += __shfl_xor(hacc[g][r], m, 64);
  if (l31 == 0) {
    #pragma unroll
    for (int g = 0; g < 4; ++g)
      *(floatx4*)&agg1[(size_t)row * D + 32 * w + 8 * g + 4 * hl] = hacc[g];
  }

  // pass-2 weights (a1 dead -> regs reusable)
  half8 a2[8];
  #pragma unroll
  for (int ks = 0; ks < 8; ++ks)
    a2[ks] = *(const half8*)(weT2 + (32 * w + l31) * D + 16 * ks + 8 * hl);

  __syncthreads();                      // e_mid visible to all waves

  // --- pass 2: T2[c][j] = sum_k We2T[c][k] e_mid[j][k] ---
  #pragma unroll
  for (int jt = 0; jt < 4; ++jt) acc[jt] = vzero;
  #pragma unroll
  for (int ks = 0; ks < 8; ++ks)
    #pragma unroll
    for (int jt = 0; jt < 4; ++jt) {
      const half8 bv = *(const half8*)
          &sE[(32 * jt + l31) * D + (((2 * ks + hl) ^ l15) << 3)];
      acc[jt] = __builtin_amdgcn_mfma_f32_32x32x16_f16(a2[ks], bv, acc[jt], 0, 0, 0);
    }

  __syncthreads();                      // all pass-2 reads complete

  // --- deposit T2 into sE (same cell mapping) ---
  #pragma unroll
  for (int jt = 0; jt < 4; ++jt) {
    const int j = 32 * jt + l31;
    #pragma unroll
    for (int g = 0; g < 4; ++g) {
      const int hidx = j * D + (((4 * w + g) ^ l15) << 3) + 4 * hl;
      half4 tv;
      #pragma unroll
      for (int r = 0; r < 4; ++r) tv[r] = (_Float16)acc[jt][4 * g + r];
      *(half4*)&sE[hidx] = tv;
    }
  }

  __syncthreads();                      // T2 complete in LDS

  // --- copy-out, unmasked j rows only (swizzled layout preserved) ---
  uint4* gdst = (uint4*)(em + (size_t)row * N * D);
  const uint4* ls = (const uint4*)sE;
  #pragma unroll
  for (int u = 0; u < 8; ++u) {
    const int idx4 = u * 256 + t;
    const int j = u * 16 + (t >> 4);
    if (sMask[j] != 0.f) gdst[idx4] = ls[idx4];
  }
}

// ---------------------------------------------------------------------------
// K5: batched node-1 + layer-2 projections. 4 rows/block (512 blocks).
//   x_mid = 0.5*(x1 + relu(x1@Wx1 + agg1@Wa1 + bn1))   (LDS only)
//   xi2 = x_mid@Wi2 + bm2 ;  xj2 = x_mid@Wj2
// ---------------------------------------------------------------------------
__global__ __launch_bounds__(256) void k_node2(
    const float* __restrict__ x1, const float* __restrict__ agg1,
    const float* __restrict__ wn1, const float* __restrict__ bn1,
    const float* __restrict__ wm2, const float* __restrict__ bm2,
    float* __restrict__ xi2, float* __restrict__ xj2) {
  const int r0 = blockIdx.x * 4;        // 512 blocks
  const int t = threadIdx.x;
  const int c = t & 127, rh = t >> 7;
  __shared__ float sIn[4][D];
  __shared__ float sAg[4][D];
  __shared__ float sXm[4][D];
  ((float2*)sIn)[t] = ((const float2*)(x1 + (size_t)r0 * D))[t];
  ((float2*)sAg)[t] = ((const float2*)(agg1 + (size_t)r0 * D))[t];
  __syncthreads();

  float acc[2];
  #pragma unroll
  for (int r = 0; r < 2; ++r) acc[r] = bn1[c];
  #pragma unroll 4
  for (int k4 = 0; k4 < D; k4 += 4) {
    const float* wb = wn1 + k4 * D + c;
    const float w0 = wb[0], w1 = wb[D], w2 = wb[2 * D], w3 = wb[3 * D];
    #pragma unroll
    for (int r = 0; r < 2; ++r) {
      const float4 xv = *(const float4*)&sIn[rh * 2 + r][k4];
      acc[r] = fmaf(xv.x, w0, acc[r]);
      acc[r] = fmaf(xv.y, w1, acc[r]);
      acc[r] = fmaf(xv.z, w2, acc[r]);
      acc[r] = fmaf(xv.w, w3, acc[r]);
    }
  }
  #pragma unroll 4
  for (int k4 = 0; k4 < D; k4 += 4) {
    const float* wb = wn1 + (D + k4) * D + c;
    const float w0 = wb[0], w1 = wb[D], w2 = wb[2 * D], w3 = wb[3 * D];
    #pragma unroll
    for (int r = 0; r < 2; ++r) {
      const float4 xv = *(const float4*)&sAg[rh * 2 + r][k4];
      acc[r] = fmaf(xv.x, w0, acc[r]);
      acc[r] = fmaf(xv.y, w1, acc[r]);
      acc[r] = fmaf(xv.z, w2, acc[r]);
      acc[r] = fmaf(xv.w, w3, acc[r]);
    }
  }
  #pragma unroll
  for (int r = 0; r < 2; ++r) {
    const float v = 0.5f * (sIn[rh * 2 + r][c] + fmaxf(acc[r], 0.f));
    sXm[rh * 2 + r][c] = v;
  }
  __syncthreads();

  float a[4];
  #pragma unroll
  for (int r = 0; r < 4; ++r) a[r] = rh ? 0.f : bm2[c];
  const float* wh = wm2 + (size_t)rh * D * D;
  #pragma unroll 4
  for (int k4 = 0; k4 < D; k4 += 4) {
    const float* wb = wh + k4 * D + c;
    const float w0 = wb[0], w1 = wb[D], w2 = wb[2 * D], w3 = wb[3 * D];
    #pragma unroll
    for (int r = 0; r < 4; ++r) {
      const float4 xv = *(const float4*)&sXm[r][k4];
      a[r] = fmaf(xv.x, w0, a[r]);
      a[r] = fmaf(xv.y, w1, a[r]);
      a[r] = fmaf(xv.z, w2, a[r]);
      a[r] = fmaf(xv.w, w3, a[r]);
    }
  }
  float* dst = rh ? xj2 : xi2;
  #pragma unroll
  for (int r = 0; r < 4; ++r) dst[(size_t)(r0 + r) * D + c] = a[r];
}

// ---------------------------------------------------------------------------
// K6: final layer streaming: msg2 = relu(xi2 + xj2 + T2)*A; rowsum over j.
// Masked j rows skipped entirely (contribution 0; saves their 256 B loads).
// ---------------------------------------------------------------------------
__global__ __launch_bounds__(256) void k_fin(
    const int* __restrict__ ei, const _Float16* __restrict__ t2,
    const float* __restrict__ xi, const float* __restrict__ xj,
    float* __restrict__ rowsum) {
  const int row = blockIdx.x;
  const int b = row >> 7;
  const int t = threadIdx.x;
  const int c8 = (t & 15) * 8, jr = t >> 4;

  __shared__ float sMask[N];
  __shared__ float hp[16][16][8];
  if (t < N) sMask[t] = (float)ei[(size_t)row * N + t];
  float xiv[8];
  *(floatx4*)&xiv[0] = *(const floatx4*)&xi[row * D + c8];
  *(floatx4*)&xiv[4] = *(const floatx4*)&xi[row * D + c8 + 4];
  __syncthreads();

  const _Float16* src = t2 + (size_t)row * N * D;
  const float* xjb = xj + (size_t)b * N * D;
  float acc8[8] = {};
  #pragma unroll
  for (int u = 0; u < 8; ++u) {
    const int j = u * 16 + jr;           // j&15 == jr
    if (sMask[j] != 0.f) {
      const half8 tv = *(const half8*)(src + j * D + (((t & 15) ^ jr) << 3));
      const floatx4 xj0 = *(const floatx4*)&xjb[j * D + c8];
      const floatx4 xj1 = *(const floatx4*)&xjb[j * D + c8 + 4];
      #pragma unroll
      for (int r = 0; r < 4; ++r) {
        acc8[r]     += fmaxf(xiv[r] + xj0[r] + (float)tv[r], 0.f);
        acc8[4 + r] += fmaxf(xiv[4 + r] + xj1[r] + (float)tv[4 + r], 0.f);
      }
    }
  }
  #pragma unroll
  for (int k = 0; k < 8; ++k) hp[jr][t & 15][k] = acc8[k];
  __syncthreads();
  if (t < D) {
    float s = 0.f;
    #pragma unroll
    for (int g = 0; g < 16; ++g) s += hp[g][t >> 3][t & 7];
    rowsum[row * D + t] = s;
  }
}

// ---------------------------------------------------------------------------
// K7: head MLP. 16 blocks.
// ---------------------------------------------------------------------------
__global__ __launch_bounds__(128) void k_head(
    const float* __restrict__ rowsum,
    const float* __restrict__ w1, const float* __restrict__ b1,
    const float* __restrict__ w2, const float* __restrict__ b2,
    const float* __restrict__ w3, const float* __restrict__ b3,
    float* __restrict__ out) {
  const int b = blockIdx.x;
  const int c = threadIdx.x;
  __shared__ float hr[D], h1r[D], h2r[D];
  const float* rs = rowsum + (size_t)b * N * D;
  float s = 0.f;
  for (int i = 0; i < N; ++i) s += rs[i * D + c];
  hr[c] = s * (1.f / (N * N));
  __syncthreads();
  float a = b1[c];
  #pragma unroll 8
  for (int k = 0; k < D; ++k) a = fmaf(hr[k], w1[k * D + c], a);
  h1r[c] = fmaxf(a, 0.f);
  __syncthreads();
  a = b2[c];
  #pragma unroll 8
  for (int k = 0; k < D; ++k) a = fmaf(h1r[k], w2[k * D + c], a);
  h2r[c] = fmaxf(a, 0.f);
  __syncthreads();
  hr[c] = h2r[c] * w3[c];
  __syncthreads();
  if (c == 0) {
    float s2 = b3[0];
    for (int k = 0; k < D; ++k) s2 += hr[k];
    out[b] = s2;
  }
}

// ---------------------------------------------------------------------------
extern "C" void kernel_launch(void* const* d_in, const int* in_sizes, int n_in,
                              void* d_out, int out_size, void* d_ws, size_t ws_size,
                              hipStream_t stream) {
  const int*   ei  = (const int*)d_in[0];
  const float* x0  = (const float*)d_in[1];
  const float* ea  = (const float*)d_in[2];
  const float* wm0 = (const float*)d_in[3];
  const float* bm0 = (const float*)d_in[4];
  const float* wn0 = (const float*)d_in[5];
  const float* bn0 = (const float*)d_in[6];
  const float* wm1 = (const float*)d_in[7];
  const float* bm1 = (const float*)d_in[8];
  const float* wn1 = (const float*)d_in[9];
  const float* bn1 = (const float*)d_in[10];
  const float* wm2 = (const float*)d_in[11];
  const float* bm2 = (const float*)d_in[12];
  const float* wh1 = (const float*)d_in[15];
  const float* bh1 = (const float*)d_in[16];
  const float* wh2 = (const float*)d_in[17];
  const float* bh2 = (const float*)d_in[18];
  const float* wh3 = (const float*)d_in[19];
  const float* bh3 = (const float*)d_in[20];
  float* out = (float*)d_out;

  _Float16* msg0h = (_Float16*)d_ws;                 // [B,N,N,D] fp16: msg0 -> T2
  _Float16* weT1  = msg0h + (size_t)B * N * N * D;
  _Float16* weT2  = weT1 + D * D;
  float* f = (float*)(weT2 + D * D);
  size_t off = 0;
  const size_t R = (size_t)B * N * D;
  float* xi0  = f + off; off += R;
  float* xj0  = f + off; off += R;
  float* x1   = f + off; off += R;
  float* xi1  = f + off; off += R;
  float* xj1  = f + off; off += R;
  float* xi2  = f + off; off += R;
  float* xj2  = f + off; off += R;
  float* rsum = f + off; off += R;

  // agg scratch: rsum buffer is dead until k_fin, so it carries agg0
  // (k_edge0 -> k_node1) and then agg1 (k_mid -> k_node2). Stream order
  // guarantees each consumer reads before the next producer overwrites.
  float* aggS = rsum;

  const int rows = B * N;   // 2048
  k_pre  <<<512 + 128, 256, 0, stream>>>(x0, wm0, bm0, wm1, wm2,
                                         xi0, xj0, weT1, weT2);
  k_edge0<<<rows, 256, 0, stream>>>(ei, ea, wm0, xi0, xj0, msg0h, aggS);
  k_node1<<<rows / 4, 256, 0, stream>>>(x0, aggS, wn0, bn0, wm1, bm1,
                                        x1, xi1, xj1);
  k_mid  <<<rows, 256, 0, stream>>>(ei, weT1, weT2, xi1, xj1, msg0h, aggS);
  k_node2<<<rows / 4, 256, 0, stream>>>(x1, aggS, wn1, bn1, wm2, bm2,
                                        xi2, xj2);
  k_fin  <<<rows, 256, 0, stream>>>(ei, msg0h, xi2, xj2, rsum);
  k_head <<<B,    128, 0, stream>>>(rsum, wh1, bh1, wh2, bh2, wh3, bh3, out);
}

// Round 7
// 214.030 us; speedup vs baseline: 1.0643x; 1.0151x over previous
//
#include <hip/hip_runtime.h>

constexpr int B = 16, N = 128, D = 128, DN0 = 64, DE0 = 16;

typedef _Float16 half8 __attribute__((ext_vector_type(8)));
typedef _Float16 half4 __attribute__((ext_vector_type(4)));
typedef float floatx4 __attribute__((ext_vector_type(4)));
typedef float floatx16 __attribute__((ext_vector_type(16)));

// async 16B global->LDS. msg0/T2 global layout is cell-swizzled
// (16B cell g of row j stored at g^(j&15)) so linear copies land
// conflict-free in LDS.
__device__ __forceinline__ void gld16(const _Float16* g, _Float16* l) {
  __builtin_amdgcn_global_load_lds(
      (const __attribute__((address_space(1))) void*)g,
      (__attribute__((address_space(3))) void*)l, 16, 0, 0);
}

// ---------------------------------------------------------------------------
// K1: merged prep. R21 (kept): xi0/xj0 BATCHED 4 rows/block (512 blocks) —
// per-row version re-streamed 32 KB of wm0 per row, 2048x redundant.
// bid >= 512 (128 blocks): WeT transposes. Weights k-major (R15).
// ---------------------------------------------------------------------------
__global__ __launch_bounds__(256) void k_pre(
    const float* __restrict__ x, const float* __restrict__ wm0,
    const float* __restrict__ bm0, const float* __restrict__ wm1,
    const float* __restrict__ wm2,
    float* __restrict__ xi0, float* __restrict__ xj0,
    _Float16* __restrict__ weT1, _Float16* __restrict__ weT2) {
  const int bid = blockIdx.x;
  const int t = threadIdx.x;
  if (bid < 512) {
    const int r0 = bid * 4;
    const int half = t >> 7, c = t & 127;
    __shared__ float sX[4][DN0];
    ((float*)sX)[t] = x[(size_t)r0 * DN0 + t];
    __syncthreads();
    float acc[4];
    #pragma unroll
    for (int r = 0; r < 4; ++r) acc[r] = half ? 0.f : bm0[c];
    const float* wb0 = wm0 + half * DN0 * D;
    #pragma unroll 4
    for (int k4 = 0; k4 < DN0; k4 += 4) {
      const float* wb = wb0 + k4 * D + c;
      const float w0 = wb[0], w1 = wb[D], w2 = wb[2 * D], w3 = wb[3 * D];
      #pragma unroll
      for (int r = 0; r < 4; ++r) {
        const float4 xv = *(const float4*)&sX[r][k4];
        acc[r] = fmaf(xv.x, w0, acc[r]);
        acc[r] = fmaf(xv.y, w1, acc[r]);
        acc[r] = fmaf(xv.z, w2, acc[r]);
        acc[r] = fmaf(xv.w, w3, acc[r]);
      }
    }
    float* dst = half ? xj0 : xi0;
    #pragma unroll
    for (int r = 0; r < 4; ++r) dst[(size_t)(r0 + r) * D + c] = acc[r];
  } else {
    const int g = (bid - 512) * 256 + t;     // 0..32767
    const int layer = g >> 14;
    const int rem = g & 16383;               // = c*D + k
    const int c = rem >> 7, k = rem & 127;
    const float* src = layer ? wm2 : wm1;
    _Float16* dst = layer ? weT2 : weT1;
    dst[rem] = (_Float16)src[(2 * D + k) * D + c];
  }
}

// ---------------------------------------------------------------------------
// K2: layer-0 edge kernel. Unconditional msg0 stores (R19): masked rows are
// exact zeros, whole buffer defined. Exports agg0. Thread map matches k_fin:
// c8=(t&15)*8, jr=t>>4, j=16p+jr.
// ---------------------------------------------------------------------------
__global__ __launch_bounds__(256) void k_edge0(
    const int* __restrict__ ei, const float* __restrict__ eattr,
    const float* __restrict__ wm0,
    const float* __restrict__ xi0, const float* __restrict__ xj0,
    _Float16* __restrict__ msg0, float* __restrict__ agg0) {
  const int row = blockIdx.x;
  const int b = row >> 7;
  const int t = threadIdx.x;
  const int c8 = (t & 15) * 8, jr = t >> 4;

  __shared__ float eb[N * 20];          // e_row [j][k] pad 20; aliased by hp
  __shared__ float w_t[DE0][D];
  __shared__ float amask[N];
  __shared__ float xi_r[D];
  float* hp = eb;                       // [16][16][8] after matmul (8 KB)

  const float4* esrc = (const float4*)(eattr + (size_t)row * N * DE0);
  const float4* wsrc = (const float4*)(wm0 + 2 * DN0 * D);
  #pragma unroll
  for (int u = 0; u < 2; ++u) {
    const int idx4 = u * 256 + t;
    const int j = idx4 >> 2;
    const int k4 = (idx4 & 3) * 4;
    *(float4*)&eb[j * 20 + k4] = esrc[idx4];
    ((float4*)&w_t[0][0])[idx4] = wsrc[idx4];
  }
  if (t < N) {
    amask[t] = (float)ei[(size_t)row * N + t];
    xi_r[t] = xi0[(size_t)row * D + t];
  }
  __syncthreads();

  // --- K=16 matmul: acc[p][q] over j=16p+jr, c=c8+q ---
  float acc[8][8] = {};
  #pragma unroll 4
  for (int k = 0; k < DE0; ++k) {
    float av[8];
    #pragma unroll
    for (int p = 0; p < 8; ++p) av[p] = eb[(16 * p + jr) * 20 + k];
    const floatx4 wv0 = *(const floatx4*)&w_t[k][c8];
    const floatx4 wv1 = *(const floatx4*)&w_t[k][c8 + 4];
    #pragma unroll
    for (int p = 0; p < 8; ++p)
      #pragma unroll
      for (int q = 0; q < 4; ++q) {
        acc[p][q]     = fmaf(av[p], wv0[q], acc[p][q]);
        acc[p][4 + q] = fmaf(av[p], wv1[q], acc[p][4 + q]);
      }
  }

  // --- epilogue: relu+mask, half8 store (swizzled, ALL rows), agg ---
  float acc8[8] = {};
  const float* xjb = xj0 + (size_t)b * N * D;
  _Float16* mrow = msg0 + (size_t)row * N * D;
  const floatx4 xiv0 = *(const floatx4*)&xi_r[c8];
  const floatx4 xiv1 = *(const floatx4*)&xi_r[c8 + 4];
  #pragma unroll
  for (int p = 0; p < 8; ++p) {
    const int j = 16 * p + jr;
    const float am = amask[j];
    const floatx4 xjv0 = *(const floatx4*)&xjb[j * D + c8];
    const floatx4 xjv1 = *(const floatx4*)&xjb[j * D + c8 + 4];
    half8 hv;
    #pragma unroll
    for (int q = 0; q < 4; ++q) {
      float v0 = fmaxf(xiv0[q] + xjv0[q] + acc[p][q], 0.f) * am;
      float v1 = fmaxf(xiv1[q] + xjv1[q] + acc[p][4 + q], 0.f) * am;
      hv[q] = (_Float16)v0;
      hv[4 + q] = (_Float16)v1;
      acc8[q] += v0;
      acc8[4 + q] += v1;
    }
    *(half8*)&mrow[j * D + (((t & 15) ^ jr) << 3)] = hv;
  }

  __syncthreads();                      // eb reads done -> safe to alias hp
  #pragma unroll
  for (int q = 0; q < 8; ++q) hp[(jr * 16 + (t & 15)) * 8 + q] = acc8[q];
  __syncthreads();
  if (t < D) {
    float s = 0.f;
    #pragma unroll
    for (int g = 0; g < 16; ++g) s += hp[(g * 16 + (t >> 3)) * 8 + (t & 7)];
    agg0[(size_t)row * D + t] = s;
  }
}

// ---------------------------------------------------------------------------
// K3: batched node-0 + layer-1 projections. 4 rows/block (512 blocks).
//   x1  = relu(x0@Wx0 + agg0@Wa0 + bn0) ; xi1 = x1@Wi1+bm1 ; xj1 = x1@Wj1
// ---------------------------------------------------------------------------
__global__ __launch_bounds__(256) void k_node1(
    const float* __restrict__ x0, const float* __restrict__ agg0,
    const float* __restrict__ wn0, const float* __restrict__ bn0,
    const float* __restrict__ wm1, const float* __restrict__ bm1,
    float* __restrict__ x1, float* __restrict__ xi1, float* __restrict__ xj1) {
  const int r0 = blockIdx.x * 4;        // 512 blocks
  const int t = threadIdx.x;
  const int c = t & 127, rh = t >> 7;
  __shared__ float sIn[4][DN0];
  __shared__ float sAg[4][D];
  __shared__ float sX1[4][D];
  ((float*)sIn)[t] = x0[(size_t)r0 * DN0 + t];
  ((float2*)sAg)[t] = ((const float2*)(agg0 + (size_t)r0 * D))[t];
  __syncthreads();

  // node0: 2 rows per thread
  float acc[2];
  #pragma unroll
  for (int r = 0; r < 2; ++r) acc[r] = bn0[c];
  #pragma unroll 4
  for (int k4 = 0; k4 < DN0; k4 += 4) {
    const float* wb = wn0 + k4 * D + c;
    const float w0 = wb[0], w1 = wb[D], w2 = wb[2 * D], w3 = wb[3 * D];
    #pragma unroll
    for (int r = 0; r < 2; ++r) {
      const float4 xv = *(const float4*)&sIn[rh * 2 + r][k4];
      acc[r] = fmaf(xv.x, w0, acc[r]);
      acc[r] = fmaf(xv.y, w1, acc[r]);
      acc[r] = fmaf(xv.z, w2, acc[r]);
      acc[r] = fmaf(xv.w, w3, acc[r]);
    }
  }
  #pragma unroll 4
  for (int k4 = 0; k4 < D; k4 += 4) {
    const float* wb = wn0 + (DN0 + k4) * D + c;
    const float w0 = wb[0], w1 = wb[D], w2 = wb[2 * D], w3 = wb[3 * D];
    #pragma unroll
    for (int r = 0; r < 2; ++r) {
      const float4 xv = *(const float4*)&sAg[rh * 2 + r][k4];
      acc[r] = fmaf(xv.x, w0, acc[r]);
      acc[r] = fmaf(xv.y, w1, acc[r]);
      acc[r] = fmaf(xv.z, w2, acc[r]);
      acc[r] = fmaf(xv.w, w3, acc[r]);
    }
  }
  #pragma unroll
  for (int r = 0; r < 2; ++r) {
    const float v = fmaxf(acc[r], 0.f);
    sX1[rh * 2 + r][c] = v;
    x1[(size_t)(r0 + rh * 2 + r) * D + c] = v;
  }
  __syncthreads();

  // xi1 (rh=0, +bm1) / xj1 (rh=1): 4 rows per thread
  float a[4];
  #pragma unroll
  for (int r = 0; r < 4; ++r) a[r] = rh ? 0.f : bm1[c];
  const float* wh = wm1 + (size_t)rh * D * D;
  #pragma unroll 4
  for (int k4 = 0; k4 < D; k4 += 4) {
    const float* wb = wh + k4 * D + c;
    const float w0 = wb[0], w1 = wb[D], w2 = wb[2 * D], w3 = wb[3 * D];
    #pragma unroll
    for (int r = 0; r < 4; ++r) {
      const float4 xv = *(const float4*)&sX1[r][k4];
      a[r] = fmaf(xv.x, w0, a[r]);
      a[r] = fmaf(xv.y, w1, a[r]);
      a[r] = fmaf(xv.z, w2, a[r]);
      a[r] = fmaf(xv.w, w3, a[r]);
    }
  }
  float* dst = rh ? xj1 : xi1;
  #pragma unroll
  for (int r = 0; r < 4; ++r) dst[(size_t)(r0 + r) * D + c] = a[r];
}

// ---------------------------------------------------------------------------
// K4: fused layer-1+2 edge kernel. R22: EXACT R19 shape restored (256 thr,
// 4 waves, full row, 2 blocks/CU, VGPR 76). Measured local optimum:
// R18 block-split ✗, R20 wave-split ✗, R21 reg-prefetch ✗ (VGPR 120,
// occupancy 24->19). xj loads stay in the epilogue — L2-hot per-batch
// panel, reuse across 128 blocks. C/D layout (m74/m101): col(j)=lane&31,
// row(c)=(reg&3)+8*(reg>>2)+4*(lane>>5).
// ---------------------------------------------------------------------------
__global__ __launch_bounds__(256, 2) void k_mid(
    const int* __restrict__ ei, const _Float16* __restrict__ weT1,
    const _Float16* __restrict__ weT2,
    const float* __restrict__ xi, const float* __restrict__ xj,
    _Float16* __restrict__ em,          // in: msg0 (swizzled), out: T2
    float* __restrict__ agg1) {
  const int row = blockIdx.x;           // 2048
  const int b = row >> 7;
  const int t = threadIdx.x;
  const int w = t >> 6;                 // c-tile base 32w
  const int lane = t & 63;
  const int l31 = lane & 31;
  const int l15 = lane & 15;
  const int hl = lane >> 5;             // k-half; c offset 4*hl

  __shared__ _Float16 sE[N * D];        // 32 KB, swizzled rows
  __shared__ float sMask[N];

  // --- async-stage msg0 row (linear copy of swizzled layout) ---
  const _Float16* gsrc = em + (size_t)row * N * D;
  #pragma unroll
  for (int u = 0; u < 8; ++u) {
    const int seg = (u * 4 + w) * 512;  // wave-uniform base, 1 KB per instr
    gld16(gsrc + seg + lane * 8, &sE[seg]);
  }

  // --- pass-1 weight frags: A[m=l31][k=16ks+8hl+e] ---
  half8 a1[8];
  #pragma unroll
  for (int ks = 0; ks < 8; ++ks)
    a1[ks] = *(const half8*)(weT1 + (32 * w + l31) * D + 16 * ks + 8 * hl);

  // --- per-lane invariants (overlap staging) ---
  floatx4 xiv[4];
  #pragma unroll
  for (int g = 0; g < 4; ++g)
    xiv[g] = *(const floatx4*)&xi[(size_t)row * D + 32 * w + 8 * g + 4 * hl];
  if (t < N) sMask[t] = (float)ei[(size_t)row * N + t];

  __syncthreads();                      // drains gld16; sMask visible

  float am[4];
  #pragma unroll
  for (int jt = 0; jt < 4; ++jt) am[jt] = sMask[32 * jt + l31];

  // --- pass 1: T1[c][j] = sum_k We1T[c][k] msg0[j][k] ---
  const floatx16 vzero = {0.f,0.f,0.f,0.f,0.f,0.f,0.f,0.f,
                          0.f,0.f,0.f,0.f,0.f,0.f,0.f,0.f};
  floatx16 acc[4];
  #pragma unroll
  for (int jt = 0; jt < 4; ++jt) acc[jt] = vzero;
  #pragma unroll
  for (int ks = 0; ks < 8; ++ks)
    #pragma unroll
    for (int jt = 0; jt < 4; ++jt) {
      const half8 bv = *(const half8*)
          &sE[(32 * jt + l31) * D + (((2 * ks + hl) ^ l15) << 3)];
      acc[jt] = __builtin_amdgcn_mfma_f32_32x32x16_f16(a1[ks], bv, acc[jt], 0, 0, 0);
    }

  __syncthreads();                      // all pass-1 reads complete

  // --- epilogue 1: msg1 -> hacc, e_mid RMW in LDS ---
  const float* xjb = xj + (size_t)b * N * D;
  floatx4 hacc[4];
  #pragma unroll
  for (int g = 0; g < 4; ++g) hacc[g] = (floatx4){0.f, 0.f, 0.f, 0.f};
  #pragma unroll
  for (int jt = 0; jt < 4; ++jt) {
    const int j = 32 * jt + l31;        // j&15 == l15
    #pragma unroll
    for (int g = 0; g < 4; ++g) {
      const int cofs = 32 * w + 8 * g + 4 * hl;
      const int hidx = j * D + (((4 * w + g) ^ l15) << 3) + 4 * hl;
      const floatx4 xjv = *(const floatx4*)&xjb[j * D + cofs];
      const half4 m0 = *(const half4*)&sE[hidx];
      half4 mid;
      floatx4 m1;
      #pragma unroll
      for (int r = 0; r < 4; ++r) {
        const float v = xiv[g][r] + xjv[r] + acc[jt][4 * g + r];
        m1[r] = fmaxf(v, 0.f) * am[jt];
        mid[r] = (_Float16)(0.5f * ((float)m0[r] + m1[r]));
      }
      *(half4*)&sE[hidx] = mid;
      hacc[g] += m1;
    }
  }

  // agg1: butterfly over l31 spans all 128 j; export direct to global
  #pragma unroll
  for (int m = 1; m < 32; m <<= 1)
    #pragma unroll
    for (int g = 0; g < 4; ++g)
      #pragma unroll
      for (int r = 0; r < 4; ++r)
        hacc[g][r] += __shfl_xor(hacc[g][r], m, 64);
  if (l31 == 0) {
    #pragma unroll
    for (int g = 0; g < 4; ++g)
      *(floatx4*)&agg1[(size_t)row * D + 32 * w + 8 * g + 4 * hl] = hacc[g];
  }

  // pass-2 weights (a1 dead -> regs reusable)
  half8 a2[8];
  #pragma unroll
  for (int ks = 0; ks < 8; ++ks)
    a2[ks] = *(const half8*)(weT2 + (32 * w + l31) * D + 16 * ks + 8 * hl);

  __syncthreads();                      // e_mid visible to all waves

  // --- pass 2: T2[c][j] = sum_k We2T[c][k] e_mid[j][k] ---
  #pragma unroll
  for (int jt = 0; jt < 4; ++jt) acc[jt] = vzero;
  #pragma unroll
  for (int ks = 0; ks < 8; ++ks)
    #pragma unroll
    for (int jt = 0; jt < 4; ++jt) {
      const half8 bv = *(const half8*)
          &sE[(32 * jt + l31) * D + (((2 * ks + hl) ^ l15) << 3)];
      acc[jt] = __builtin_amdgcn_mfma_f32_32x32x16_f16(a2[ks], bv, acc[jt], 0, 0, 0);
    }

  __syncthreads();                      // all pass-2 reads complete

  // --- deposit T2 into sE (same cell mapping) ---
  #pragma unroll
  for (int jt = 0; jt < 4; ++jt) {
    const int j = 32 * jt + l31;
    #pragma unroll
    for (int g = 0; g < 4; ++g) {
      const int hidx = j * D + (((4 * w + g) ^ l15) << 3) + 4 * hl;
      half4 tv;
      #pragma unroll
      for (int r = 0; r < 4; ++r) tv[r] = (_Float16)acc[jt][4 * g + r];
      *(half4*)&sE[hidx] = tv;
    }
  }

  __syncthreads();                      // T2 complete in LDS

  // --- copy-out, unmasked j rows only (swizzled layout preserved) ---
  uint4* gdst = (uint4*)(em + (size_t)row * N * D);
  const uint4* ls = (const uint4*)sE;
  #pragma unroll
  for (int u = 0; u < 8; ++u) {
    const int idx4 = u * 256 + t;
    const int j = u * 16 + (t >> 4);
    if (sMask[j] != 0.f) gdst[idx4] = ls[idx4];
  }
}

// ---------------------------------------------------------------------------
// K5: batched node-1 + layer-2 projections. 4 rows/block (512 blocks).
//   x_mid = 0.5*(x1 + relu(x1@Wx1 + agg1@Wa1 + bn1))   (LDS only)
//   xi2 = x_mid@Wi2 + bm2 ;  xj2 = x_mid@Wj2
// ---------------------------------------------------------------------------
__global__ __launch_bounds__(256) void k_node2(
    const float* __restrict__ x1, const float* __restrict__ agg1,
    const float* __restrict__ wn1, const float* __restrict__ bn1,
    const float* __restrict__ wm2, const float* __restrict__ bm2,
    float* __restrict__ xi2, float* __restrict__ xj2) {
  const int r0 = blockIdx.x * 4;        // 512 blocks
  const int t = threadIdx.x;
  const int c = t & 127, rh = t >> 7;
  __shared__ float sIn[4][D];
  __shared__ float sAg[4][D];
  __shared__ float sXm[4][D];
  ((float2*)sIn)[t] = ((const float2*)(x1 + (size_t)r0 * D))[t];
  ((float2*)sAg)[t] = ((const float2*)(agg1 + (size_t)r0 * D))[t];
  __syncthreads();

  float acc[2];
  #pragma unroll
  for (int r = 0; r < 2; ++r) acc[r] = bn1[c];
  #pragma unroll 4
  for (int k4 = 0; k4 < D; k4 += 4) {
    const float* wb = wn1 + k4 * D + c;
    const float w0 = wb[0], w1 = wb[D], w2 = wb[2 * D], w3 = wb[3 * D];
    #pragma unroll
    for (int r = 0; r < 2; ++r) {
      const float4 xv = *(const float4*)&sIn[rh * 2 + r][k4];
      acc[r] = fmaf(xv.x, w0, acc[r]);
      acc[r] = fmaf(xv.y, w1, acc[r]);
      acc[r] = fmaf(xv.z, w2, acc[r]);
      acc[r] = fmaf(xv.w, w3, acc[r]);
    }
  }
  #pragma unroll 4
  for (int k4 = 0; k4 < D; k4 += 4) {
    const float* wb = wn1 + (D + k4) * D + c;
    const float w0 = wb[0], w1 = wb[D], w2 = wb[2 * D], w3 = wb[3 * D];
    #pragma unroll
    for (int r = 0; r < 2; ++r) {
      const float4 xv = *(const float4*)&sAg[rh * 2 + r][k4];
      acc[r] = fmaf(xv.x, w0, acc[r]);
      acc[r] = fmaf(xv.y, w1, acc[r]);
      acc[r] = fmaf(xv.z, w2, acc[r]);
      acc[r] = fmaf(xv.w, w3, acc[r]);
    }
  }
  #pragma unroll
  for (int r = 0; r < 2; ++r) {
    const float v = 0.5f * (sIn[rh * 2 + r][c] + fmaxf(acc[r], 0.f));
    sXm[rh * 2 + r][c] = v;
  }
  __syncthreads();

  float a[4];
  #pragma unroll
  for (int r = 0; r < 4; ++r) a[r] = rh ? 0.f : bm2[c];
  const float* wh = wm2 + (size_t)rh * D * D;
  #pragma unroll 4
  for (int k4 = 0; k4 < D; k4 += 4) {
    const float* wb = wh + k4 * D + c;
    const float w0 = wb[0], w1 = wb[D], w2 = wb[2 * D], w3 = wb[3 * D];
    #pragma unroll
    for (int r = 0; r < 4; ++r) {
      const float4 xv = *(const float4*)&sXm[r][k4];
      a[r] = fmaf(xv.x, w0, a[r]);
      a[r] = fmaf(xv.y, w1, a[r]);
      a[r] = fmaf(xv.z, w2, a[r]);
      a[r] = fmaf(xv.w, w3, a[r]);
    }
  }
  float* dst = rh ? xj2 : xi2;
  #pragma unroll
  for (int r = 0; r < 4; ++r) dst[(size_t)(r0 + r) * D + c] = a[r];
}

// ---------------------------------------------------------------------------
// K6: final layer streaming: msg2 = relu(xi2 + xj2 + T2)*A; rowsum over j.
// Masked j rows skipped entirely (contribution 0; saves their 256 B loads).
// ---------------------------------------------------------------------------
__global__ __launch_bounds__(256) void k_fin(
    const int* __restrict__ ei, const _Float16* __restrict__ t2,
    const float* __restrict__ xi, const float* __restrict__ xj,
    float* __restrict__ rowsum) {
  const int row = blockIdx.x;
  const int b = row >> 7;
  const int t = threadIdx.x;
  const int c8 = (t & 15) * 8, jr = t >> 4;

  __shared__ float sMask[N];
  __shared__ float hp[16][16][8];
  if (t < N) sMask[t] = (float)ei[(size_t)row * N + t];
  float xiv[8];
  *(floatx4*)&xiv[0] = *(const floatx4*)&xi[row * D + c8];
  *(floatx4*)&xiv[4] = *(const floatx4*)&xi[row * D + c8 + 4];
  __syncthreads();

  const _Float16* src = t2 + (size_t)row * N * D;
  const float* xjb = xj + (size_t)b * N * D;
  float acc8[8] = {};
  #pragma unroll
  for (int u = 0; u < 8; ++u) {
    const int j = u * 16 + jr;           // j&15 == jr
    if (sMask[j] != 0.f) {
      const half8 tv = *(const half8*)(src + j * D + (((t & 15) ^ jr) << 3));
      const floatx4 xj0 = *(const floatx4*)&xjb[j * D + c8];
      const floatx4 xj1 = *(const floatx4*)&xjb[j * D + c8 + 4];
      #pragma unroll
      for (int r = 0; r < 4; ++r) {
        acc8[r]     += fmaxf(xiv[r] + xj0[r] + (float)tv[r], 0.f);
        acc8[4 + r] += fmaxf(xiv[4 + r] + xj1[r] + (float)tv[4 + r], 0.f);
      }
    }
  }
  #pragma unroll
  for (int k = 0; k < 8; ++k) hp[jr][t & 15][k] = acc8[k];
  __syncthreads();
  if (t < D) {
    float s = 0.f;
    #pragma unroll
    for (int g = 0; g < 16; ++g) s += hp[g][t >> 3][t & 7];
    rowsum[row * D + t] = s;
  }
}

// ---------------------------------------------------------------------------
// K7: head MLP. 16 blocks.
// ---------------------------------------------------------------------------
__global__ __launch_bounds__(128) void k_head(
    const float* __restrict__ rowsum,
    const float* __restrict__ w1, const float* __restrict__ b1,
    const float* __restrict__ w2, const float* __restrict__ b2,
    const float* __restrict__ w3, const float* __restrict__ b3,
    float* __restrict__ out) {
  const int b = blockIdx.x;
  const int c = threadIdx.x;
  __shared__ float hr[D], h1r[D], h2r[D];
  const float* rs = rowsum + (size_t)b * N * D;
  float s = 0.f;
  for (int i = 0; i < N; ++i) s += rs[i * D + c];
  hr[c] = s * (1.f / (N * N));
  __syncthreads();
  float a = b1[c];
  #pragma unroll 8
  for (int k = 0; k < D; ++k) a = fmaf(hr[k], w1[k * D + c], a);
  h1r[c] = fmaxf(a, 0.f);
  __syncthreads();
  a = b2[c];
  #pragma unroll 8
  for (int k = 0; k < D; ++k) a = fmaf(h1r[k], w2[k * D + c], a);
  h2r[c] = fmaxf(a, 0.f);
  __syncthreads();
  hr[c] = h2r[c] * w3[c];
  __syncthreads();
  if (c == 0) {
    float s2 = b3[0];
    for (int k = 0; k < D; ++k) s2 += hr[k];
    out[b] = s2;
  }
}

// ---------------------------------------------------------------------------
extern "C" void kernel_launch(void* const* d_in, const int* in_sizes, int n_in,
                              void* d_out, int out_size, void* d_ws, size_t ws_size,
                              hipStream_t stream) {
  const int*   ei  = (const int*)d_in[0];
  const float* x0  = (const float*)d_in[1];
  const float* ea  = (const float*)d_in[2];
  const float* wm0 = (const float*)d_in[3];
  const float* bm0 = (const float*)d_in[4];
  const float* wn0 = (const float*)d_in[5];
  const float* bn0 = (const float*)d_in[6];
  const float* wm1 = (const float*)d_in[7];
  const float* bm1 = (const float*)d_in[8];
  const float* wn1 = (const float*)d_in[9];
  const float* bn1 = (const float*)d_in[10];
  const float* wm2 = (const float*)d_in[11];
  const float* bm2 = (const float*)d_in[12];
  const float* wh1 = (const float*)d_in[15];
  const float* bh1 = (const float*)d_in[16];
  const float* wh2 = (const float*)d_in[17];
  const float* bh2 = (const float*)d_in[18];
  const float* wh3 = (const float*)d_in[19];
  const float* bh3 = (const float*)d_in[20];
  float* out = (float*)d_out;

  _Float16* msg0h = (_Float16*)d_ws;                 // [B,N,N,D] fp16: msg0 -> T2
  _Float16* weT1  = msg0h + (size_t)B * N * N * D;
  _Float16* weT2  = weT1 + D * D;
  float* f = (float*)(weT2 + D * D);
  size_t off = 0;
  const size_t R = (size_t)B * N * D;
  float* xi0  = f + off; off += R;
  float* xj0  = f + off; off += R;
  float* x1   = f + off; off += R;
  float* xi1  = f + off; off += R;
  float* xj1  = f + off; off += R;
  float* xi2  = f + off; off += R;
  float* xj2  = f + off; off += R;
  float* rsum = f + off; off += R;

  // agg scratch: rsum buffer is dead until k_fin, so it carries agg0
  // (k_edge0 -> k_node1) and then agg1 (k_mid -> k_node2). Stream order
  // guarantees each consumer reads before the next producer overwrites.
  float* aggS = rsum;

  const int rows = B * N;   // 2048
  k_pre  <<<512 + 128, 256, 0, stream>>>(x0, wm0, bm0, wm1, wm2,
                                         xi0, xj0, weT1, weT2);
  k_edge0<<<rows, 256, 0, stream>>>(ei, ea, wm0, xi0, xj0, msg0h, aggS);
  k_node1<<<rows / 4, 256, 0, stream>>>(x0, aggS, wn0, bn0, wm1, bm1,
                                        x1, xi1, xj1);
  k_mid  <<<rows, 256, 0, stream>>>(ei, weT1, weT2, xi1, xj1, msg0h, aggS);
  k_node2<<<rows / 4, 256, 0, stream>>>(x1, aggS, wn1, bn1, wm2, bm2,
                                        xi2, xj2);
  k_fin  <<<rows, 256, 0, stream>>>(ei, msg0h, xi2, xj2, rsum);
  k_head <<<B,    128, 0, stream>>>(rsum, wh1, bh1, wh2, bh2, wh3, bh3, out);
}